// Round 1
// baseline (289.937 us; speedup 1.0000x reference)
//
#include <hip/hip_runtime.h>
#include <stdint.h>

#define N_NODES 524288
#define BLOCK 128
#define NUM_BLOCKS 4096
#define MAX_KV 64
#define GRAPH_WEIGHT 0.3f

// ws float-index layout
#define WS_SUMP 0            // [4096] sum of keep*p per block
#define WS_CNTK 4096         // [4096] keep count per block
#define WS_QCNT 8192         // [4096] uncertain count per block
#define WS_BCE  12288        // scalar: sum(bce * sup)
#define WS_SCNT 12289        // scalar: sum(sup)
#define WS_GNUM 12290        // scalar: sum(blk_loss * valid)
#define WS_GCNT 12291        // scalar: count(valid)
#define WS_FLAG 12292        // int: 1 if masks are byte-packed (numpy bool), 0 if int32

__device__ __forceinline__ bool read_mask(const void* p, int i, int byteflag) {
    if (byteflag) return ((const uint8_t*)p)[i] != 0;
    return ((const int*)p)[i] != 0;
}

// Detect mask storage: view first N/4 words (always in-bounds for both layouts).
// Byte-packed bools (p=0.2) produce many words > 1; int32 0/1 never does.
__global__ void detect_kernel(const unsigned int* sup_u32, int* flag) {
    int idx = blockIdx.x * blockDim.x + threadIdx.x;
    const int n = N_NODES / 4;
    int found = 0;
    for (int i = idx; i < n; i += gridDim.x * blockDim.x)
        if (sup_u32[i] > 1u) found = 1;
    if (__any(found) && (threadIdx.x & 63) == 0)
        atomicOr(flag, 1);
}

__global__ void __launch_bounds__(BLOCK)
k1_per_block(const float* __restrict__ logits, const float* __restrict__ targets,
             const void* __restrict__ sup, const void* __restrict__ ign,
             float* __restrict__ ws) {
    const int b = blockIdx.x, t = threadIdx.x;
    const int i = b * BLOCK + t;
    const int bf = ((const int*)ws)[WS_FLAG];
    float x  = logits[i];
    float tg = targets[i];
    bool s = read_mask(sup, i, bf);
    bool g = read_mask(ign, i, bf);
    // stable softplus(x) - t*x
    float bce = fmaxf(x, 0.f) + log1pf(expf(-fabsf(x))) - tg * x;
    float p = 1.f / (1.f + expf(-x));
    float v0 = g ? 0.f : p;              // keep * p
    float v1 = g ? 0.f : 1.f;            // keep count
    float v2 = (!g && !s) ? 1.f : 0.f;   // uncertain count
    float v3 = s ? bce : 0.f;            // sup bce
    float v4 = s ? 1.f : 0.f;            // sup count
    for (int off = 32; off > 0; off >>= 1) {
        v0 += __shfl_down(v0, off);
        v1 += __shfl_down(v1, off);
        v2 += __shfl_down(v2, off);
        v3 += __shfl_down(v3, off);
        v4 += __shfl_down(v4, off);
    }
    __shared__ float sh[2][5];
    if ((t & 63) == 0) {
        int w = t >> 6;
        sh[w][0] = v0; sh[w][1] = v1; sh[w][2] = v2; sh[w][3] = v3; sh[w][4] = v4;
    }
    __syncthreads();
    if (t == 0) {
        ws[WS_SUMP + b] = sh[0][0] + sh[1][0];
        ws[WS_CNTK + b] = sh[0][1] + sh[1][1];
        ws[WS_QCNT + b] = sh[0][2] + sh[1][2];
        atomicAdd(&ws[WS_BCE],  sh[0][3] + sh[1][3]);
        atomicAdd(&ws[WS_SCNT], sh[0][4] + sh[1][4]);
    }
}

__global__ void __launch_bounds__(BLOCK)
k2_graph(const float* __restrict__ logits,
         const void* __restrict__ sup, const void* __restrict__ ign,
         const int* __restrict__ kvi, const int* __restrict__ kvn,
         float* __restrict__ ws) {
    const int b = blockIdx.x, t = threadIdx.x;
    const int bf = ((const int*)ws)[WS_FLAG];
    __shared__ float sh_nmean, sh_ncnt;
    if (t < 64) {
        float ns = 0.f, nc = 0.f;
        int num = kvn[b];
        if (t < num) {
            int j = kvi[b * MAX_KV + t];
            ns = ws[WS_SUMP + j];
            nc = ws[WS_CNTK + j];
        }
        for (int off = 32; off > 0; off >>= 1) {
            ns += __shfl_down(ns, off);
            nc += __shfl_down(nc, off);
        }
        if (t == 0) {
            sh_ncnt  = nc;
            sh_nmean = ns / fmaxf(nc, 1.f);
        }
    }
    __syncthreads();
    const float nmean = sh_nmean;
    const float ncnt  = sh_ncnt;
    const int i = b * BLOCK + t;
    float x = logits[i];
    bool s = read_mask(sup, i, bf);
    bool g = read_mask(ign, i, bf);
    float p = 1.f / (1.f + expf(-x));
    float d = p - nmean;
    float v = (!g && !s) ? d * d : 0.f;
    for (int off = 32; off > 0; off >>= 1)
        v += __shfl_down(v, off);
    __shared__ float shv[2];
    if ((t & 63) == 0) shv[t >> 6] = v;
    __syncthreads();
    if (t == 0) {
        float vs = shv[0] + shv[1];
        float qc = ws[WS_QCNT + b];
        if (qc > 0.f && ncnt > 0.f) {
            atomicAdd(&ws[WS_GNUM], vs / fmaxf(qc, 1.f));
            atomicAdd(&ws[WS_GCNT], 1.f);
        }
    }
}

__global__ void k3_final(const float* __restrict__ ws, float* __restrict__ out) {
    float bs = ws[WS_BCE], sc = ws[WS_SCNT];
    float loss_sup = (sc > 0.f) ? bs / fmaxf(sc, 1.f) : 0.f;
    float gn = ws[WS_GNUM], gc = ws[WS_GCNT];
    float loss_graph = gn / fmaxf(gc, 1.f);
    out[0] = loss_sup + GRAPH_WEIGHT * loss_graph;
}

extern "C" void kernel_launch(void* const* d_in, const int* in_sizes, int n_in,
                              void* d_out, int out_size, void* d_ws, size_t ws_size,
                              hipStream_t stream) {
    const float* logits  = (const float*)d_in[0];
    const float* targets = (const float*)d_in[1];
    const void*  sup     = d_in[2];
    const void*  ign     = d_in[3];
    const int*   kvi     = (const int*)d_in[4];
    const int*   kvn     = (const int*)d_in[5];
    float* out = (float*)d_out;
    float* ws  = (float*)d_ws;

    hipMemsetAsync(d_ws, 0, (WS_FLAG + 1) * sizeof(float), stream);
    detect_kernel<<<64, 256, 0, stream>>>((const unsigned int*)sup, (int*)ws + WS_FLAG);
    k1_per_block<<<NUM_BLOCKS, BLOCK, 0, stream>>>(logits, targets, sup, ign, ws);
    k2_graph<<<NUM_BLOCKS, BLOCK, 0, stream>>>(logits, sup, ign, kvi, kvn, ws);
    k3_final<<<1, 1, 0, stream>>>(ws, out);
}

// Round 2
// 82.123 us; speedup vs baseline: 3.5305x; 3.5305x over previous
//
#include <hip/hip_runtime.h>
#include <stdint.h>

#define N_NODES 524288
#define BLOCK 128
#define NUM_BLOCKS 4096
#define MAX_KV 64
#define GRAPH_WEIGHT 0.3f

// ws float-index layout (all per-block partial arrays; no atomics anywhere)
#define WS_SUMP 0            // [4096] sum of keep*p per block
#define WS_CNTK 4096         // [4096] keep count per block
#define WS_QCNT 8192         // [4096] uncertain count per block
#define WS_BCEP 12288        // [4096] per-block sum(bce*sup)
#define WS_SUPP 16384        // [4096] per-block sum(sup)
#define WS_GNUM 20480        // [4096] per-block blk_loss*valid
#define WS_GCNT 24576        // [4096] per-block valid

__device__ __forceinline__ bool read_mask(const void* p, int i, int byteflag) {
    if (byteflag) return ((const uint8_t*)p)[i] != 0;
    return ((const int*)p)[i] != 0;
}

// Block-local mask-layout detection: all blocks scan the same first 256 words
// of sup. Byte-packed bools (p=0.2) give words>1 with P(miss)=0.512^256~=3e-75;
// an int32 0/1 array can never produce a word >1. 256 words are in-bounds for
// both layouts (byte: 131072 words, int32: 524288 words) and L2-broadcast.
__device__ __forceinline__ int detect_byteflag(const void* sup, int t, int* sh_flag) {
    if (t == 0) *sh_flag = 0;
    __syncthreads();
    const unsigned int* w = (const unsigned int*)sup;
    unsigned int a = w[t] | w[t + 128];  // OR>1  <=>  either>1 (values<=1 are {0,1})
    if (a > 1u) *sh_flag = 1;            // benign same-value race
    __syncthreads();
    return *sh_flag;
}

__global__ void __launch_bounds__(BLOCK)
k1_per_block(const float* __restrict__ logits, const float* __restrict__ targets,
             const void* __restrict__ sup, const void* __restrict__ ign,
             float* __restrict__ ws) {
    const int b = blockIdx.x, t = threadIdx.x;
    const int i = b * BLOCK + t;
    __shared__ int sh_flag;
    const int bf = detect_byteflag(sup, t, &sh_flag);
    float x  = logits[i];
    float tg = targets[i];
    bool s = read_mask(sup, i, bf);
    bool g = read_mask(ign, i, bf);
    // stable softplus(x) - t*x
    float bce = fmaxf(x, 0.f) + log1pf(expf(-fabsf(x))) - tg * x;
    float p = 1.f / (1.f + expf(-x));
    float v0 = g ? 0.f : p;              // keep * p
    float v1 = g ? 0.f : 1.f;            // keep count
    float v2 = (!g && !s) ? 1.f : 0.f;   // uncertain count
    float v3 = s ? bce : 0.f;            // sup bce
    float v4 = s ? 1.f : 0.f;            // sup count
    for (int off = 32; off > 0; off >>= 1) {
        v0 += __shfl_down(v0, off);
        v1 += __shfl_down(v1, off);
        v2 += __shfl_down(v2, off);
        v3 += __shfl_down(v3, off);
        v4 += __shfl_down(v4, off);
    }
    __shared__ float sh[2][5];
    if ((t & 63) == 0) {
        int w = t >> 6;
        sh[w][0] = v0; sh[w][1] = v1; sh[w][2] = v2; sh[w][3] = v3; sh[w][4] = v4;
    }
    __syncthreads();
    if (t == 0) {
        ws[WS_SUMP + b] = sh[0][0] + sh[1][0];
        ws[WS_CNTK + b] = sh[0][1] + sh[1][1];
        ws[WS_QCNT + b] = sh[0][2] + sh[1][2];
        ws[WS_BCEP + b] = sh[0][3] + sh[1][3];
        ws[WS_SUPP + b] = sh[0][4] + sh[1][4];
    }
}

__global__ void __launch_bounds__(BLOCK)
k2_graph(const float* __restrict__ logits,
         const void* __restrict__ sup, const void* __restrict__ ign,
         const int* __restrict__ kvi, const int* __restrict__ kvn,
         float* __restrict__ ws) {
    const int b = blockIdx.x, t = threadIdx.x;
    __shared__ int sh_flag;
    const int bf = detect_byteflag(sup, t, &sh_flag);
    __shared__ float sh_nmean, sh_ncnt;
    if (t < 64) {
        float ns = 0.f, nc = 0.f;
        int num = kvn[b];
        if (t < num) {
            int j = kvi[b * MAX_KV + t];
            ns = ws[WS_SUMP + j];
            nc = ws[WS_CNTK + j];
        }
        for (int off = 32; off > 0; off >>= 1) {
            ns += __shfl_down(ns, off);
            nc += __shfl_down(nc, off);
        }
        if (t == 0) {
            sh_ncnt  = nc;
            sh_nmean = ns / fmaxf(nc, 1.f);
        }
    }
    __syncthreads();
    const float nmean = sh_nmean;
    const float ncnt  = sh_ncnt;
    const int i = b * BLOCK + t;
    float x = logits[i];
    bool s = read_mask(sup, i, bf);
    bool g = read_mask(ign, i, bf);
    float p = 1.f / (1.f + expf(-x));
    float d = p - nmean;
    float v = (!g && !s) ? d * d : 0.f;
    for (int off = 32; off > 0; off >>= 1)
        v += __shfl_down(v, off);
    __shared__ float shv[2];
    if ((t & 63) == 0) shv[t >> 6] = v;
    __syncthreads();
    if (t == 0) {
        float vs = shv[0] + shv[1];
        float qc = ws[WS_QCNT + b];
        bool valid = (qc > 0.f) && (ncnt > 0.f);
        ws[WS_GNUM + b] = valid ? vs / fmaxf(qc, 1.f) : 0.f;
        ws[WS_GCNT + b] = valid ? 1.f : 0.f;
    }
}

// Single-block reduction of the 4 per-block partial arrays -> final scalar.
__global__ void __launch_bounds__(256)
k3_final(const float* __restrict__ ws, float* __restrict__ out) {
    const int t = threadIdx.x;
    float bce = 0.f, scnt = 0.f, gnum = 0.f, gcnt = 0.f;
    for (int b = t; b < NUM_BLOCKS; b += 256) {
        bce  += ws[WS_BCEP + b];
        scnt += ws[WS_SUPP + b];
        gnum += ws[WS_GNUM + b];
        gcnt += ws[WS_GCNT + b];
    }
    for (int off = 32; off > 0; off >>= 1) {
        bce  += __shfl_down(bce, off);
        scnt += __shfl_down(scnt, off);
        gnum += __shfl_down(gnum, off);
        gcnt += __shfl_down(gcnt, off);
    }
    __shared__ float sh[4][4];
    if ((t & 63) == 0) {
        int w = t >> 6;
        sh[w][0] = bce; sh[w][1] = scnt; sh[w][2] = gnum; sh[w][3] = gcnt;
    }
    __syncthreads();
    if (t == 0) {
        float bs = sh[0][0] + sh[1][0] + sh[2][0] + sh[3][0];
        float sc = sh[0][1] + sh[1][1] + sh[2][1] + sh[3][1];
        float gn = sh[0][2] + sh[1][2] + sh[2][2] + sh[3][2];
        float gc = sh[0][3] + sh[1][3] + sh[2][3] + sh[3][3];
        float loss_sup = (sc > 0.f) ? bs / fmaxf(sc, 1.f) : 0.f;
        float loss_graph = gn / fmaxf(gc, 1.f);
        out[0] = loss_sup + GRAPH_WEIGHT * loss_graph;
    }
}

extern "C" void kernel_launch(void* const* d_in, const int* in_sizes, int n_in,
                              void* d_out, int out_size, void* d_ws, size_t ws_size,
                              hipStream_t stream) {
    const float* logits  = (const float*)d_in[0];
    const float* targets = (const float*)d_in[1];
    const void*  sup     = d_in[2];
    const void*  ign     = d_in[3];
    const int*   kvi     = (const int*)d_in[4];
    const int*   kvn     = (const int*)d_in[5];
    float* out = (float*)d_out;
    float* ws  = (float*)d_ws;

    k1_per_block<<<NUM_BLOCKS, BLOCK, 0, stream>>>(logits, targets, sup, ign, ws);
    k2_graph<<<NUM_BLOCKS, BLOCK, 0, stream>>>(logits, sup, ign, kvi, kvn, ws);
    k3_final<<<1, 256, 0, stream>>>(ws, out);
}